// Round 9
// baseline (91.362 us; speedup 1.0000x reference)
//
#include <hip/hip_runtime.h>
#include <cstdint>

#define CC 1000
#define KK 2
#define DD 128

typedef short bf16x8 __attribute__((ext_vector_type(8)));
typedef float f32x16 __attribute__((ext_vector_type(16)));
typedef int   i32x4  __attribute__((ext_vector_type(4)));

__device__ __forceinline__ uint32_t f2bf(float f) {
    uint32_t x = __builtin_bit_cast(uint32_t, f);
    return (x + 0x7FFFu + ((x >> 16) & 1u)) >> 16;
}
__device__ __forceinline__ uint32_t pk2(float lo, float hi) {
    return f2bf(lo) | (f2bf(hi) << 16);
}
__device__ __forceinline__ f32x16 zero16() {
    f32x16 v;
    #pragma unroll
    for (int p = 0; p < 16; ++p) v[p] = 0.f;
    return v;
}

// 8 packed-bf16 words = one 32x32x16 B-fragment pair, fully scalarized.
struct Frag8 { uint32_t a0, a1, a2, a3, b0, b1, b2, b3; };

__device__ __forceinline__ bf16x8 flo(const Frag8 f) {
    i32x4 t; t[0] = (int)f.a0; t[1] = (int)f.a1; t[2] = (int)f.a2; t[3] = (int)f.a3;
    return __builtin_bit_cast(bf16x8, t);
}
__device__ __forceinline__ bf16x8 fhi(const Frag8 f) {
    i32x4 t; t[0] = (int)f.b0; t[1] = (int)f.b1; t[2] = (int)f.b2; t[3] = (int)f.b3;
    return __builtin_bit_cast(bf16x8, t);
}

// C-layout fp32 tile -> B-fragment words (mapping verified rounds 4..8).
__device__ __forceinline__ Frag8 build_frags(const f32x16 t, int hp) {
    uint32_t W0 = pk2(t[0],  t[1]),  W1 = pk2(t[2],  t[3]);
    uint32_t W2 = pk2(t[4],  t[5]),  W3 = pk2(t[6],  t[7]);
    uint32_t W4 = pk2(t[8],  t[9]),  W5 = pk2(t[10], t[11]);
    uint32_t W6 = pk2(t[12], t[13]), W7 = pk2(t[14], t[15]);
    uint32_t s0 = (uint32_t)__shfl_xor((int)W0, 32, 64);
    uint32_t s1 = (uint32_t)__shfl_xor((int)W1, 32, 64);
    uint32_t s2 = (uint32_t)__shfl_xor((int)W2, 32, 64);
    uint32_t s3 = (uint32_t)__shfl_xor((int)W3, 32, 64);
    uint32_t s4 = (uint32_t)__shfl_xor((int)W4, 32, 64);
    uint32_t s5 = (uint32_t)__shfl_xor((int)W5, 32, 64);
    uint32_t s6 = (uint32_t)__shfl_xor((int)W6, 32, 64);
    uint32_t s7 = (uint32_t)__shfl_xor((int)W7, 32, 64);
    Frag8 f;
    f.a0 = hp ? s2 : W0;  f.a1 = hp ? s3 : W1;
    f.a2 = hp ? W2 : s0;  f.a3 = hp ? W3 : s1;
    f.b0 = hp ? s6 : W4;  f.b1 = hp ? s7 : W5;
    f.b2 = hp ? W6 : s4;  f.b3 = hp ? W7 : s5;
    return f;
}

__device__ __forceinline__ f32x16 off_apply(const char* Ep, const Frag8 yj, f32x16 acc) {
    bf16x8 A0 = *(const bf16x8*)(Ep);
    bf16x8 A1 = *(const bf16x8*)(Ep + 32);
    acc = __builtin_amdgcn_mfma_f32_32x32x16_bf16(A0, flo(yj), acc, 0, 0, 0);
    acc = __builtin_amdgcn_mfma_f32_32x32x16_bf16(A1, fhi(yj), acc, 0, 0, 0);
    return acc;
}
__device__ __forceinline__ f32x16 m_solve(const char* Mp, const Frag8 tf) {
    bf16x8 MA0 = *(const bf16x8*)(Mp);
    bf16x8 MA1 = *(const bf16x8*)(Mp + 32);
    f32x16 y = zero16();
    y = __builtin_amdgcn_mfma_f32_32x32x16_bf16(MA0, flo(tf), y, 0, 0, 0);
    y = __builtin_amdgcn_mfma_f32_32x32x16_bf16(MA1, fhi(tf), y, 0, 0, 0);
    return y;
}

// LDS layout (rows stride 80B = bank-spread):
//   [0,15360)      Eoff: 6 off-diag blocks, A-layout, holds -L_ij
//   [15360,25600)  Sm:   4 diag blocks, first -S_i, overwritten by M'_i
//   [25600,35840)  Tt:   4 diag blocks, (I - S_i) transposed (B-layout)
//
// OCCUPANCY RECIPE (empirical, rounds 2..8): __launch_bounds__(256, 1) is the
// ONLY lever that relaxes the RA budget on this toolchain (round 8: VGPR 120,
// WRITE 8MB spill-free; 512-thread variants were pinned to 64 VGPR + 135MB
// scratch regardless of amdgpu_waves_per_eu / LDS padding).
__global__ __launch_bounds__(256, 1) void mda_kernel(
    const float* __restrict__ z,          // (B, D)
    const float* __restrict__ mu,         // (C, K, D)
    const float* __restrict__ logits_pi,  // (C, K)
    const float* __restrict__ covL,       // (C, K, D, D)
    const float* __restrict__ prior,      // (C,)
    float* __restrict__ out)              // (B, C)
{
    __shared__ __align__(16) char E[35840];
    __shared__ float RD[DD];
    __shared__ float LG[2];

    const int c   = blockIdx.x;
    const int tid = threadIdx.x;
    const int w   = tid >> 6, l = tid & 63, l31 = l & 31, hp = l >> 5;
    const int colA = w * 64 + l31;              // chain A batch column
    const int colB = colA + 32;                 // chain B batch column
    const float* zbA = z + (size_t)colA * DD;
    const float* zbB = z + (size_t)colB * DD;
    const int off = l31 * 80 + 16 * hp;         // per-lane fragment offset in a block

    float lpA0 = 0.f, lpA1 = 0.f, lpB0 = 0.f, lpB1 = 0.f;

    for (int k = 0; k < KK; ++k) {
        const float* Lm  = covL + (int64_t)(c*KK + k) * (DD*DD);
        const float* muv = mu + (size_t)(c*KK + k) * DD;

        __syncthreads();                        // protect E/RD/LG reuse across k
        // ---- phase A: rdiag + logdet (waves 0,1)
        if (tid < DD) {
            float dg = Lm[(size_t)tid * DD + tid];
            RD[tid] = 1.0f / dg;
            float lg = __logf(dg);
            #pragma unroll
            for (int o = 32; o; o >>= 1) lg += __shfl_down(lg, o, 64);
            if (l == 0) LG[tid >> 6] = lg;
        }
        __syncthreads();
        const float sld = LG[0] + LG[1];

        // ---- phase B: stage E (coalesced float4 row loads; once per class)
        {
            #pragma unroll
            for (int rep = 0; rep < 6; ++rep) {  // 6 off-diag blocks * 32 rows * 8 float4
                int t2 = tid + 256*rep;
                int blk = t2 >> 8, r = (t2 >> 3) & 31, c4 = t2 & 7;
                // block list (i,j): (1,0)(2,0)(2,1)(3,0)(3,1)(3,2)
                int ib = 1 + (blk >= 1) + (blk >= 3);
                int jb = blk - ((ib * (ib - 1)) >> 1);
                float4 v = *(const float4*)(Lm + (size_t)(32*ib + r)*DD + 32*jb + 4*c4);
                uint2 u; u.x = pk2(-v.x, -v.y); u.y = pk2(-v.z, -v.w);
                *(uint2*)(E + blk*2560 + r*80 + 8*c4) = u;
            }
            #pragma unroll
            for (int rep = 0; rep < 4; ++rep) {  // 4 diag blocks * 32 rows * 8 float4
                int t3 = tid + 256*rep;
                int ib = t3 >> 8, r = (t3 >> 3) & 31, c4 = t3 & 7;
                float4 v = *(const float4*)(Lm + (size_t)(32*ib + r)*DD + 32*ib + 4*c4);
                float rdr = RD[32*ib + r];
                int n0 = 4*c4;
                float se0 = (n0+0 < r) ? -v.x*rdr : 0.f;
                float se1 = (n0+1 < r) ? -v.y*rdr : 0.f;
                float se2 = (n0+2 < r) ? -v.z*rdr : 0.f;
                float se3 = (n0+3 < r) ? -v.w*rdr : 0.f;
                char* tt = E + 25600 + ib*2560 + 2*r;
                *(unsigned short*)(tt + (n0+0)*80) = (unsigned short)f2bf((n0+0 == r) ? 1.f : se0);
                *(unsigned short*)(tt + (n0+1)*80) = (unsigned short)f2bf((n0+1 == r) ? 1.f : se1);
                *(unsigned short*)(tt + (n0+2)*80) = (unsigned short)f2bf((n0+2 == r) ? 1.f : se2);
                *(unsigned short*)(tt + (n0+3)*80) = (unsigned short)f2bf((n0+3 == r) ? 1.f : se3);
                uint2 u; u.x = pk2(se0, se1); u.y = pk2(se2, se3);
                *(uint2*)(E + 15360 + ib*2560 + r*80 + 8*c4) = u;
            }
        }
        __syncthreads();

        // ---- M' compute: wave w owns tile w.  M' = (I + (-S)(I-S)) * D^-1
        {
            const char* SmB = E + 15360 + w*2560;
            const char* TtB = E + 25600 + w*2560;
            bf16x8 A0 = *(const bf16x8*)(SmB + l31*80 + 16*hp);
            bf16x8 A1 = *(const bf16x8*)(SmB + l31*80 + 32 + 16*hp);
            bf16x8 B0 = *(const bf16x8*)(TtB + l31*80 + 16*hp);
            bf16x8 B1 = *(const bf16x8*)(TtB + l31*80 + 32 + 16*hp);
            f32x16 mm = zero16();
            mm = __builtin_amdgcn_mfma_f32_32x32x16_bf16(A0, B0, mm, 0,0,0);
            mm = __builtin_amdgcn_mfma_f32_32x32x16_bf16(A1, B1, mm, 0,0,0);
            float rdn = RD[32*w + l31];          // column scale (n = l31)
            char* SmW = E + 15360 + w*2560;
            #pragma unroll
            for (int p = 0; p < 16; ++p) {
                int rowp = (p&3) + 8*(p>>2) + 4*hp;
                float mval = (mm[p] + ((rowp == l31) ? 1.f : 0.f)) * rdn;
                *(unsigned short*)(SmW + rowp*80 + 2*l31) = (unsigned short)f2bf(mval);
            }
        }
        __syncthreads();

        // ---- solve: TWO independent chains per wave (cols colA, colB) — ILP
        float maccA = 0.f, maccB = 0.f;
        f32x16 accA, accB, yvA, yvB;
        Frag8 tfA, tfB, y0A, y0B, y1A, y1B, y2A, y2B;

        #define LOAD_R(i, acc, zb)                                               \
            do {                                                                 \
                _Pragma("unroll")                                                \
                for (int q = 0; q < 4; ++q) {                                    \
                    float4 zv = *(const float4*)((zb) + 32*(i) + 8*q + 4*hp);    \
                    float4 mv = *(const float4*)(muv + 32*(i) + 8*q + 4*hp);     \
                    (acc)[4*q+0] = zv.x - mv.x;  (acc)[4*q+1] = zv.y - mv.y;     \
                    (acc)[4*q+2] = zv.z - mv.z;  (acc)[4*q+3] = zv.w - mv.w;     \
                }                                                                \
            } while (0)
        #define SQACC(macc, yv)                                                  \
            do {                                                                 \
                _Pragma("unroll")                                                \
                for (int p = 0; p < 16; ++p) (macc) += (yv)[p] * (yv)[p];        \
            } while (0)

        // i = 0
        LOAD_R(0, accA, zbA);            LOAD_R(0, accB, zbB);
        tfA = build_frags(accA, hp);     tfB = build_frags(accB, hp);
        yvA = m_solve(E + 15360 + 0*2560 + off, tfA);
        yvB = m_solve(E + 15360 + 0*2560 + off, tfB);
        SQACC(maccA, yvA);               SQACC(maccB, yvB);
        y0A = build_frags(yvA, hp);      y0B = build_frags(yvB, hp);
        // i = 1   (off-diag block (1,0) = blk 0)
        LOAD_R(1, accA, zbA);            LOAD_R(1, accB, zbB);
        accA = off_apply(E + 0*2560 + off, y0A, accA);
        accB = off_apply(E + 0*2560 + off, y0B, accB);
        tfA = build_frags(accA, hp);     tfB = build_frags(accB, hp);
        yvA = m_solve(E + 15360 + 1*2560 + off, tfA);
        yvB = m_solve(E + 15360 + 1*2560 + off, tfB);
        SQACC(maccA, yvA);               SQACC(maccB, yvB);
        y1A = build_frags(yvA, hp);      y1B = build_frags(yvB, hp);
        // i = 2   (blocks (2,0)=1, (2,1)=2)
        LOAD_R(2, accA, zbA);            LOAD_R(2, accB, zbB);
        accA = off_apply(E + 1*2560 + off, y0A, accA);
        accB = off_apply(E + 1*2560 + off, y0B, accB);
        accA = off_apply(E + 2*2560 + off, y1A, accA);
        accB = off_apply(E + 2*2560 + off, y1B, accB);
        tfA = build_frags(accA, hp);     tfB = build_frags(accB, hp);
        yvA = m_solve(E + 15360 + 2*2560 + off, tfA);
        yvB = m_solve(E + 15360 + 2*2560 + off, tfB);
        SQACC(maccA, yvA);               SQACC(maccB, yvB);
        y2A = build_frags(yvA, hp);      y2B = build_frags(yvB, hp);
        // i = 3   (blocks (3,0)=3, (3,1)=4, (3,2)=5)
        LOAD_R(3, accA, zbA);            LOAD_R(3, accB, zbB);
        accA = off_apply(E + 3*2560 + off, y0A, accA);
        accB = off_apply(E + 3*2560 + off, y0B, accB);
        accA = off_apply(E + 4*2560 + off, y1A, accA);
        accB = off_apply(E + 4*2560 + off, y1B, accB);
        accA = off_apply(E + 5*2560 + off, y2A, accA);
        accB = off_apply(E + 5*2560 + off, y2B, accB);
        tfA = build_frags(accA, hp);     tfB = build_frags(accB, hp);
        yvA = m_solve(E + 15360 + 3*2560 + off, tfA);
        yvB = m_solve(E + 15360 + 3*2560 + off, tfB);
        SQACC(maccA, yvA);               SQACC(maccB, yvB);
        #undef LOAD_R
        #undef SQACC

        maccA += __shfl_xor(maccA, 32, 64);     // combine row-halves per column
        maccB += __shfl_xor(maccB, 32, 64);

        const float CST = 235.2482645f;         // 128*log(2*pi)
        float lA = -0.5f * (maccA + 2.f * sld + CST);
        float lB = -0.5f * (maccB + 2.f * sld + CST);
        if (k == 0) { lpA0 = lA; lpB0 = lB; }
        else        { lpA1 = lA; lpB1 = lB; }
    }

    // ---- epilogue: prior + LSE_k(lp + logpi) - LSE_k(logpi), both chains
    if (hp == 0) {
        float pi0 = logits_pi[c*2+0], pi1 = logits_pi[c*2+1];
        float mp = fmaxf(pi0, pi1);
        float lsepi = mp + __logf(__expf(pi0-mp) + __expf(pi1-mp));
        float pr = prior[c];
        {
            float t0 = lpA0 + pi0, t1 = lpA1 + pi1;
            float mt = fmaxf(t0, t1);
            out[(size_t)colA * CC + c] =
                pr + mt + __logf(__expf(t0-mt) + __expf(t1-mt)) - lsepi;
        }
        {
            float t0 = lpB0 + pi0, t1 = lpB1 + pi1;
            float mt = fmaxf(t0, t1);
            out[(size_t)colB * CC + c] =
                pr + mt + __logf(__expf(t0-mt) + __expf(t1-mt)) - lsepi;
        }
    }
}

extern "C" void kernel_launch(void* const* d_in, const int* in_sizes, int n_in,
                              void* d_out, int out_size, void* d_ws, size_t ws_size,
                              hipStream_t stream) {
    const float* z         = (const float*)d_in[0];
    const float* mu        = (const float*)d_in[1];
    const float* logits_pi = (const float*)d_in[2];
    const float* covL      = (const float*)d_in[3];
    const float* prior     = (const float*)d_in[4];
    float* out = (float*)d_out;

    hipLaunchKernelGGL(mda_kernel, dim3(CC), dim3(256), 0, stream,
                       z, mu, logits_pi, covL, prior, out);
}

// Round 10
// 62.538 us; speedup vs baseline: 1.4609x; 1.4609x over previous
//
#include <hip/hip_runtime.h>
#include <cstdint>

#define CC 1000
#define KK 2
#define DD 128

typedef short bf16x8 __attribute__((ext_vector_type(8)));
typedef float f32x16 __attribute__((ext_vector_type(16)));
typedef int   i32x4  __attribute__((ext_vector_type(4)));

__device__ __forceinline__ uint32_t f2bf(float f) {
    uint32_t x = __builtin_bit_cast(uint32_t, f);
    return (x + 0x7FFFu + ((x >> 16) & 1u)) >> 16;
}
__device__ __forceinline__ uint32_t pk2(float lo, float hi) {
    return f2bf(lo) | (f2bf(hi) << 16);
}
__device__ __forceinline__ f32x16 zero16() {
    f32x16 v;
    #pragma unroll
    for (int p = 0; p < 16; ++p) v[p] = 0.f;
    return v;
}

// 8 packed-bf16 words = one 32x32x16 B-fragment pair, fully scalarized.
struct Frag8 { uint32_t a0, a1, a2, a3, b0, b1, b2, b3; };

__device__ __forceinline__ bf16x8 flo(const Frag8 f) {
    i32x4 t; t[0] = (int)f.a0; t[1] = (int)f.a1; t[2] = (int)f.a2; t[3] = (int)f.a3;
    return __builtin_bit_cast(bf16x8, t);
}
__device__ __forceinline__ bf16x8 fhi(const Frag8 f) {
    i32x4 t; t[0] = (int)f.b0; t[1] = (int)f.b1; t[2] = (int)f.b2; t[3] = (int)f.b3;
    return __builtin_bit_cast(bf16x8, t);
}

// C-layout fp32 tile -> B-fragment words (mapping verified rounds 4..9).
__device__ __forceinline__ Frag8 build_frags(const f32x16 t, int hp) {
    uint32_t W0 = pk2(t[0],  t[1]),  W1 = pk2(t[2],  t[3]);
    uint32_t W2 = pk2(t[4],  t[5]),  W3 = pk2(t[6],  t[7]);
    uint32_t W4 = pk2(t[8],  t[9]),  W5 = pk2(t[10], t[11]);
    uint32_t W6 = pk2(t[12], t[13]), W7 = pk2(t[14], t[15]);
    uint32_t s0 = (uint32_t)__shfl_xor((int)W0, 32, 64);
    uint32_t s1 = (uint32_t)__shfl_xor((int)W1, 32, 64);
    uint32_t s2 = (uint32_t)__shfl_xor((int)W2, 32, 64);
    uint32_t s3 = (uint32_t)__shfl_xor((int)W3, 32, 64);
    uint32_t s4 = (uint32_t)__shfl_xor((int)W4, 32, 64);
    uint32_t s5 = (uint32_t)__shfl_xor((int)W5, 32, 64);
    uint32_t s6 = (uint32_t)__shfl_xor((int)W6, 32, 64);
    uint32_t s7 = (uint32_t)__shfl_xor((int)W7, 32, 64);
    Frag8 f;
    f.a0 = hp ? s2 : W0;  f.a1 = hp ? s3 : W1;
    f.a2 = hp ? W2 : s0;  f.a3 = hp ? W3 : s1;
    f.b0 = hp ? s6 : W4;  f.b1 = hp ? s7 : W5;
    f.b2 = hp ? W6 : s4;  f.b3 = hp ? W7 : s5;
    return f;
}

__device__ __forceinline__ f32x16 off_apply(const char* Ep, const Frag8 yj, f32x16 acc) {
    bf16x8 A0 = *(const bf16x8*)(Ep);
    bf16x8 A1 = *(const bf16x8*)(Ep + 32);
    acc = __builtin_amdgcn_mfma_f32_32x32x16_bf16(A0, flo(yj), acc, 0, 0, 0);
    acc = __builtin_amdgcn_mfma_f32_32x32x16_bf16(A1, fhi(yj), acc, 0, 0, 0);
    return acc;
}
__device__ __forceinline__ f32x16 m_solve(const char* Mp, const Frag8 tf) {
    bf16x8 MA0 = *(const bf16x8*)(Mp);
    bf16x8 MA1 = *(const bf16x8*)(Mp + 32);
    f32x16 y = zero16();
    y = __builtin_amdgcn_mfma_f32_32x32x16_bf16(MA0, flo(tf), y, 0, 0, 0);
    y = __builtin_amdgcn_mfma_f32_32x32x16_bf16(MA1, fhi(tf), y, 0, 0, 0);
    return y;
}

// LDS layout (rows stride 80B = bank-spread):
//   [0,15360)      Eoff: 6 off-diag blocks, A-layout, holds -L_ij
//   [15360,25600)  Sm:   4 diag blocks, first -S_i, overwritten by M'_i
//   [25600,35840)  Tt:   4 diag blocks, (I - S_i) transposed (B-layout)
//
// OCCUPANCY RECIPE (rounds 2..9): __launch_bounds__(256, 1) is the only lever
// that relaxes the RA budget on this toolchain. Round 8: VGPR 120 -> 4 blocks/CU,
// spill-free. Round 9 (2 chains): VGPR 180 -> 2 waves/SIMD -> REGRESSION.
// Parallelism must come from MORE BLOCKS, not fatter waves -> k split across grid.
__global__ __launch_bounds__(256, 1) void mda_partial_kernel(
    const float* __restrict__ z,          // (B, D)
    const float* __restrict__ mu,         // (C, K, D)
    const float* __restrict__ covL,       // (C, K, D, D)
    float* __restrict__ ws)               // (K, B, C) partial lp
{
    __shared__ __align__(16) char E[35840];
    __shared__ float RD[DD];
    __shared__ float LG[2];

    const int bid = blockIdx.x;           // = c*4 + k*2 + h
    const int c   = bid >> 2;
    const int k   = (bid >> 1) & 1;
    const int h   = bid & 1;
    const int tid = threadIdx.x;
    const int w   = tid >> 6, l = tid & 63, l31 = l & 31, hp = l >> 5;
    const int bcol = h * 128 + w * 32 + l31;    // this lane's batch column
    const float* zb = z + (size_t)bcol * DD;
    const int off = l31 * 80 + 16 * hp;         // per-lane fragment offset in a block

    const float* Lm  = covL + (int64_t)(c*KK + k) * (DD*DD);
    const float* muv = mu + (size_t)(c*KK + k) * DD;

    // ---- phase A: rdiag + logdet (waves 0,1)
    if (tid < DD) {
        float dg = Lm[(size_t)tid * DD + tid];
        RD[tid] = 1.0f / dg;
        float lg = __logf(dg);
        #pragma unroll
        for (int o = 32; o; o >>= 1) lg += __shfl_down(lg, o, 64);
        if (l == 0) LG[tid >> 6] = lg;
    }
    __syncthreads();
    const float sld = LG[0] + LG[1];

    // ---- phase B: stage E (coalesced float4 row loads)
    {
        #pragma unroll
        for (int rep = 0; rep < 6; ++rep) {  // 6 off-diag blocks * 32 rows * 8 float4
            int t2 = tid + 256*rep;
            int blk = t2 >> 8, r = (t2 >> 3) & 31, c4 = t2 & 7;
            // block list (i,j): (1,0)(2,0)(2,1)(3,0)(3,1)(3,2)
            int ib = 1 + (blk >= 1) + (blk >= 3);
            int jb = blk - ((ib * (ib - 1)) >> 1);
            float4 v = *(const float4*)(Lm + (size_t)(32*ib + r)*DD + 32*jb + 4*c4);
            uint2 u; u.x = pk2(-v.x, -v.y); u.y = pk2(-v.z, -v.w);
            *(uint2*)(E + blk*2560 + r*80 + 8*c4) = u;
        }
        #pragma unroll
        for (int rep = 0; rep < 4; ++rep) {  // 4 diag blocks * 32 rows * 8 float4
            int t3 = tid + 256*rep;
            int ib = t3 >> 8, r = (t3 >> 3) & 31, c4 = t3 & 7;
            float4 v = *(const float4*)(Lm + (size_t)(32*ib + r)*DD + 32*ib + 4*c4);
            float rdr = RD[32*ib + r];
            int n0 = 4*c4;
            float se0 = (n0+0 < r) ? -v.x*rdr : 0.f;
            float se1 = (n0+1 < r) ? -v.y*rdr : 0.f;
            float se2 = (n0+2 < r) ? -v.z*rdr : 0.f;
            float se3 = (n0+3 < r) ? -v.w*rdr : 0.f;
            char* tt = E + 25600 + ib*2560 + 2*r;
            *(unsigned short*)(tt + (n0+0)*80) = (unsigned short)f2bf((n0+0 == r) ? 1.f : se0);
            *(unsigned short*)(tt + (n0+1)*80) = (unsigned short)f2bf((n0+1 == r) ? 1.f : se1);
            *(unsigned short*)(tt + (n0+2)*80) = (unsigned short)f2bf((n0+2 == r) ? 1.f : se2);
            *(unsigned short*)(tt + (n0+3)*80) = (unsigned short)f2bf((n0+3 == r) ? 1.f : se3);
            uint2 u; u.x = pk2(se0, se1); u.y = pk2(se2, se3);
            *(uint2*)(E + 15360 + ib*2560 + r*80 + 8*c4) = u;
        }
    }
    __syncthreads();

    // ---- M' compute: wave w owns tile w.  M' = (I + (-S)(I-S)) * D^-1
    {
        const char* SmB = E + 15360 + w*2560;
        const char* TtB = E + 25600 + w*2560;
        bf16x8 A0 = *(const bf16x8*)(SmB + l31*80 + 16*hp);
        bf16x8 A1 = *(const bf16x8*)(SmB + l31*80 + 32 + 16*hp);
        bf16x8 B0 = *(const bf16x8*)(TtB + l31*80 + 16*hp);
        bf16x8 B1 = *(const bf16x8*)(TtB + l31*80 + 32 + 16*hp);
        f32x16 mm = zero16();
        mm = __builtin_amdgcn_mfma_f32_32x32x16_bf16(A0, B0, mm, 0,0,0);
        mm = __builtin_amdgcn_mfma_f32_32x32x16_bf16(A1, B1, mm, 0,0,0);
        float rdn = RD[32*w + l31];          // column scale (n = l31)
        char* SmW = E + 15360 + w*2560;
        #pragma unroll
        for (int p = 0; p < 16; ++p) {
            int rowp = (p&3) + 8*(p>>2) + 4*hp;
            float mval = (mm[p] + ((rowp == l31) ? 1.f : 0.f)) * rdn;
            *(unsigned short*)(SmW + rowp*80 + 2*l31) = (unsigned short)f2bf(mval);
        }
    }
    __syncthreads();

    // ---- solve: single chain per lane-column, hand-unrolled, zero local arrays
    float macc = 0.f;
    f32x16 acc, yv;
    Frag8 tf, y0, y1, y2;

    #define LOAD_R(i)                                                        \
        do {                                                                 \
            _Pragma("unroll")                                                \
            for (int q = 0; q < 4; ++q) {                                    \
                float4 zv = *(const float4*)(zb + 32*(i) + 8*q + 4*hp);      \
                float4 mv = *(const float4*)(muv + 32*(i) + 8*q + 4*hp);     \
                acc[4*q+0] = zv.x - mv.x;  acc[4*q+1] = zv.y - mv.y;         \
                acc[4*q+2] = zv.z - mv.z;  acc[4*q+3] = zv.w - mv.w;         \
            }                                                                \
        } while (0)
    #define SQACC()                                                          \
        do {                                                                 \
            _Pragma("unroll")                                                \
            for (int p = 0; p < 16; ++p) macc += yv[p] * yv[p];              \
        } while (0)

    // i = 0
    LOAD_R(0);
    tf = build_frags(acc, hp);
    yv = m_solve(E + 15360 + 0*2560 + off, tf);
    SQACC();
    y0 = build_frags(yv, hp);
    // i = 1   (off-diag block (1,0) = blk 0)
    LOAD_R(1);
    acc = off_apply(E + 0*2560 + off, y0, acc);
    tf = build_frags(acc, hp);
    yv = m_solve(E + 15360 + 1*2560 + off, tf);
    SQACC();
    y1 = build_frags(yv, hp);
    // i = 2   (blocks (2,0)=1, (2,1)=2)
    LOAD_R(2);
    acc = off_apply(E + 1*2560 + off, y0, acc);
    acc = off_apply(E + 2*2560 + off, y1, acc);
    tf = build_frags(acc, hp);
    yv = m_solve(E + 15360 + 2*2560 + off, tf);
    SQACC();
    y2 = build_frags(yv, hp);
    // i = 3   (blocks (3,0)=3, (3,1)=4, (3,2)=5)
    LOAD_R(3);
    acc = off_apply(E + 3*2560 + off, y0, acc);
    acc = off_apply(E + 4*2560 + off, y1, acc);
    acc = off_apply(E + 5*2560 + off, y2, acc);
    tf = build_frags(acc, hp);
    yv = m_solve(E + 15360 + 3*2560 + off, tf);
    SQACC();
    #undef LOAD_R
    #undef SQACC

    macc += __shfl_xor(macc, 32, 64);        // combine row-halves per column

    const float CST = 235.2482645f;          // 128*log(2*pi)
    float lp = -0.5f * (macc + 2.f * sld + CST);
    if (hp == 0) {
        // ws layout (K, B, C): same 4KB-stride scatter the round-8 out-write used
        ws[(size_t)k * (256 * CC) + (size_t)bcol * CC + c] = lp;
    }
}

// out[b,c] = prior[c] + LSE_k(lp_k + pi_k) - LSE_k(pi_k). Fully coalesced.
__global__ __launch_bounds__(256) void mda_combine_kernel(
    const float* __restrict__ ws,         // (K, B, C)
    const float* __restrict__ logits_pi,  // (C, K)
    const float* __restrict__ prior,      // (C,)
    float* __restrict__ out)              // (B, C)
{
    int idx = blockIdx.x * 256 + threadIdx.x;    // = b*CC + c, 256000 total
    int c = idx % CC;
    float lp0 = ws[idx];
    float lp1 = ws[256 * CC + idx];
    float pi0 = logits_pi[c*2+0], pi1 = logits_pi[c*2+1];
    float mp = fmaxf(pi0, pi1);
    float lsepi = mp + __logf(__expf(pi0-mp) + __expf(pi1-mp));
    float t0 = lp0 + pi0, t1 = lp1 + pi1;
    float mt = fmaxf(t0, t1);
    out[idx] = prior[c] + mt + __logf(__expf(t0-mt) + __expf(t1-mt)) - lsepi;
}

extern "C" void kernel_launch(void* const* d_in, const int* in_sizes, int n_in,
                              void* d_out, int out_size, void* d_ws, size_t ws_size,
                              hipStream_t stream) {
    const float* z         = (const float*)d_in[0];
    const float* mu        = (const float*)d_in[1];
    const float* logits_pi = (const float*)d_in[2];
    const float* covL      = (const float*)d_in[3];
    const float* prior     = (const float*)d_in[4];
    float* out = (float*)d_out;
    float* ws  = (float*)d_ws;   // needs 2*256*1000*4 = 2.048 MB

    hipLaunchKernelGGL(mda_partial_kernel, dim3(4*CC), dim3(256), 0, stream,
                       z, mu, covL, ws);
    hipLaunchKernelGGL(mda_combine_kernel, dim3(256 * CC / 256), dim3(256), 0, stream,
                       ws, logits_pi, prior, out);
}